// Round 1
// baseline (254.410 us; speedup 1.0000x reference)
//
#include <hip/hip_runtime.h>

// Projector: out[n,p,o] = x@Wd^T + bd + softmax_l((x@W1^T)·(t@W2^T)^T) @ (t@W3^T + b3)
// N=16, HW=3136 (=49*64), L=64, C_IN=256, C_OUT=512, D=256. fp32 in/out.
// Strategy: all GEMMs via v_mfma_f32_16x16x32_f16 (f16 staging, fp32 accum).
// f16 chosen over bf16: same MFMA rate, 4x smaller input-rounding eps -> score
// noise sigma ~0.02 vs ~0.08, comfortably under the 0.124 absmax threshold.

typedef unsigned short u16;
using half8 = __attribute__((ext_vector_type(8))) _Float16;
using f32x4 = __attribute__((ext_vector_type(4))) float;

__device__ __forceinline__ u16 f2h(float f) {
  _Float16 h = (_Float16)f;            // RNE
  union { _Float16 h; u16 u; } cv; cv.h = h;
  return cv.u;
}

__device__ __forceinline__ f32x4 mfma16(half8 a, half8 b, f32x4 c) {
  return __builtin_amdgcn_mfma_f32_16x16x32_f16(a, b, c, 0, 0, 0);
}

// ---------------------------------------------------------------------------
// K0: fp32 -> f16 conversion of W1, W2, W3, Wd, t
// ---------------------------------------------------------------------------
__global__ __launch_bounds__(256) void cvt_kernel(
    const float* __restrict__ W1, const float* __restrict__ W2,
    const float* __restrict__ W3, const float* __restrict__ Wd,
    const float* __restrict__ t,
    u16* __restrict__ W1h, u16* __restrict__ W2h, u16* __restrict__ W3h,
    u16* __restrict__ Wdh, u16* __restrict__ th) {
  int i = blockIdx.x * 256 + threadIdx.x;   // grid covers 262144
  if (i < 65536)  { W1h[i] = f2h(W1[i]); W2h[i] = f2h(W2[i]); }
  if (i < 131072) { W3h[i] = f2h(W3[i]); Wdh[i] = f2h(Wd[i]); }
  if (i < 262144) { th[i]  = f2h(t[i]); }
}

// ---------------------------------------------------------------------------
// K1: t_q[n,l,e] = sum_d t[n,l,d] * W2[e,d]   -> f16, row-major over e
// grid 16 (one block per n), 4 waves; wave w owns e-cols [64w, 64w+64)
// ---------------------------------------------------------------------------
__global__ __launch_bounds__(256) void tq_kernel(
    const u16* __restrict__ th, const u16* __restrict__ W2h,
    u16* __restrict__ tqh) {
  const int n = blockIdx.x;
  const int tid = threadIdx.x, w = tid >> 6, lane = tid & 63;
  const int quad = lane >> 4, l16 = lane & 15;

  f32x4 acc[4][4];
  #pragma unroll
  for (int mt = 0; mt < 4; ++mt)
    #pragma unroll
    for (int nt = 0; nt < 4; ++nt) acc[mt][nt] = (f32x4){0.f, 0.f, 0.f, 0.f};

  #pragma unroll
  for (int k = 0; k < 8; ++k) {
    half8 a[4];
    #pragma unroll
    for (int mt = 0; mt < 4; ++mt)
      a[mt] = *(const half8*)(th + (size_t)(n*64 + mt*16 + l16)*256 + k*32 + quad*8);
    #pragma unroll
    for (int nt = 0; nt < 4; ++nt) {
      half8 b = *(const half8*)(W2h + (size_t)(w*64 + nt*16 + l16)*256 + k*32 + quad*8);
      #pragma unroll
      for (int mt = 0; mt < 4; ++mt) acc[mt][nt] = mfma16(a[mt], b, acc[mt][nt]);
    }
  }
  #pragma unroll
  for (int mt = 0; mt < 4; ++mt)
    #pragma unroll
    for (int nt = 0; nt < 4; ++nt)
      #pragma unroll
      for (int r = 0; r < 4; ++r) {
        int l = mt*16 + quad*4 + r;
        int e = w*64 + nt*16 + l16;
        tqh[(size_t)(n*64 + l)*256 + e] = f2h(acc[mt][nt][r]);
      }
}

// ---------------------------------------------------------------------------
// K2: t3T[n,o,l] = sum_d W3[o,d]*t[n,l,d] + b3[o]  (computed directly
// transposed: A = W3 rows (m=o), B = t rows (n=l)). grid 16*8.
// ---------------------------------------------------------------------------
__global__ __launch_bounds__(256) void t3t_kernel(
    const u16* __restrict__ th, const u16* __restrict__ W3h,
    const float* __restrict__ b3, u16* __restrict__ t3Th) {
  const int n = blockIdx.x >> 3, ob = blockIdx.x & 7;
  const int tid = threadIdx.x, w = tid >> 6, lane = tid & 63;
  const int quad = lane >> 4, l16 = lane & 15;
  const int o0 = ob*64 + w*16;

  f32x4 acc[4];
  #pragma unroll
  for (int nt = 0; nt < 4; ++nt) acc[nt] = (f32x4){0.f, 0.f, 0.f, 0.f};

  #pragma unroll
  for (int k = 0; k < 8; ++k) {
    half8 a = *(const half8*)(W3h + (size_t)(o0 + l16)*256 + k*32 + quad*8);
    #pragma unroll
    for (int nt = 0; nt < 4; ++nt) {
      half8 b = *(const half8*)(th + (size_t)(n*64 + nt*16 + l16)*256 + k*32 + quad*8);
      acc[nt] = mfma16(a, b, acc[nt]);
    }
  }
  #pragma unroll
  for (int nt = 0; nt < 4; ++nt)
    #pragma unroll
    for (int r = 0; r < 4; ++r) {
      int o = o0 + quad*4 + r;
      int l = nt*16 + l16;
      t3Th[(size_t)(n*512 + o)*64 + l] = f2h(acc[nt][r] + b3[o]);
    }
}

// ---------------------------------------------------------------------------
// K3: main fused kernel. grid 784 = 16 n * 49 row-tiles of 64.
// LDS: xs 64x264 (x tile, +8 pad -> row stride == 4 banks mod 32, 2-way free),
//      xq 64x136 (x_q half, 128 cols at a time), aw 64x72 (softmax probs).
// Total 60,416 B < 64 KB static limit.
// ---------------------------------------------------------------------------
__global__ __launch_bounds__(256) void main_kernel(
    const float* __restrict__ x, const u16* __restrict__ W1h,
    const u16* __restrict__ Wdh, const u16* __restrict__ tqh,
    const u16* __restrict__ t3Th, const float* __restrict__ bd,
    float* __restrict__ out) {
  __shared__ u16 xs[64*264];
  __shared__ u16 xq[64*136];
  __shared__ u16 aw[64*72];

  const int bid = blockIdx.x;
  const int n = bid / 49;
  const int pt = bid - n*49;
  const int m0 = pt * 64;
  const int tid = threadIdx.x, w = tid >> 6, lane = tid & 63;
  const int quad = lane >> 4, l16 = lane & 15;

  // ---- stage x tile: 64x256 fp32 -> f16 LDS (coalesced float4) ----
  {
    const float4* xg = (const float4*)(x + (size_t)(n*3136 + m0)*256);
    #pragma unroll
    for (int it = 0; it < 16; ++it) {
      int idx = it*256 + tid;
      int r = idx >> 6, c4 = idx & 63;
      float4 v = xg[idx];
      ushort4 u;
      u.x = f2h(v.x); u.y = f2h(v.y); u.z = f2h(v.z); u.w = f2h(v.w);
      *(ushort4*)(&xs[r*264 + c4*4]) = u;
    }
  }
  __syncthreads();

  f32x4 acc2[4];
  #pragma unroll
  for (int lt = 0; lt < 4; ++lt) acc2[lt] = (f32x4){0.f, 0.f, 0.f, 0.f};

  // ---- GEMM1 (x_q = x@W1^T) + GEMM2 (scores = x_q@t_q^T), K-halved so the
  //      x_q LDS round-trip buffer is only 64x136 ----
  #pragma unroll
  for (int h = 0; h < 2; ++h) {
    f32x4 acc1[4][2];
    #pragma unroll
    for (int mt = 0; mt < 4; ++mt)
      #pragma unroll
      for (int nt = 0; nt < 2; ++nt) acc1[mt][nt] = (f32x4){0.f, 0.f, 0.f, 0.f};

    #pragma unroll
    for (int k = 0; k < 8; ++k) {
      half8 a[4];
      #pragma unroll
      for (int mt = 0; mt < 4; ++mt)
        a[mt] = *(const half8*)(&xs[(mt*16 + l16)*264 + k*32 + quad*8]);
      #pragma unroll
      for (int nt = 0; nt < 2; ++nt) {
        half8 b = *(const half8*)(W1h + (size_t)(h*128 + w*32 + nt*16 + l16)*256 + k*32 + quad*8);
        #pragma unroll
        for (int mt = 0; mt < 4; ++mt) acc1[mt][nt] = mfma16(a[mt], b, acc1[mt][nt]);
      }
    }
    __syncthreads();  // prior iteration's xq fully consumed by all waves
    #pragma unroll
    for (int mt = 0; mt < 4; ++mt)
      #pragma unroll
      for (int nt = 0; nt < 2; ++nt)
        #pragma unroll
        for (int r = 0; r < 4; ++r)
          xq[(mt*16 + quad*4 + r)*136 + w*32 + nt*16 + l16] = f2h(acc1[mt][nt][r]);
    __syncthreads();

    #pragma unroll
    for (int k2 = 0; k2 < 4; ++k2) {
      half8 a = *(const half8*)(&xq[(w*16 + l16)*136 + k2*32 + quad*8]);
      #pragma unroll
      for (int lt = 0; lt < 4; ++lt) {
        half8 b = *(const half8*)(tqh + (size_t)(n*64 + lt*16 + l16)*256 + h*128 + k2*32 + quad*8);
        acc2[lt] = mfma16(a, b, acc2[lt]);
      }
    }
  }

  // ---- softmax over l (row m = w*16 + quad*4 + r; 64 logits spread across
  //      the quad's 16 lanes x 4 tiles; shfl_xor masks 1..8 stay in-quad) ----
  #pragma unroll
  for (int r = 0; r < 4; ++r) {
    float s0 = acc2[0][r], s1 = acc2[1][r], s2 = acc2[2][r], s3 = acc2[3][r];
    float mx = fmaxf(fmaxf(s0, s1), fmaxf(s2, s3));
    #pragma unroll
    for (int off = 8; off >= 1; off >>= 1) mx = fmaxf(mx, __shfl_xor(mx, off, 64));
    float e0 = __expf(s0 - mx), e1 = __expf(s1 - mx);
    float e2 = __expf(s2 - mx), e3 = __expf(s3 - mx);
    float s = e0 + e1 + e2 + e3;
    #pragma unroll
    for (int off = 8; off >= 1; off >>= 1) s += __shfl_xor(s, off, 64);
    float inv = 1.0f / s;
    int row = (w*16 + quad*4 + r)*72;
    aw[row +  0 + l16] = f2h(e0 * inv);
    aw[row + 16 + l16] = f2h(e1 * inv);
    aw[row + 32 + l16] = f2h(e2 * inv);
    aw[row + 48 + l16] = f2h(e3 * inv);
  }
  __syncthreads();

  // ---- GEMM3 (probs @ t3) + GEMM4 (x @ Wd^T) share one accumulator;
  //      wave w owns output cols [128w, 128w+128) ----
  f32x4 acc[4][8];
  #pragma unroll
  for (int mt = 0; mt < 4; ++mt)
    #pragma unroll
    for (int ot = 0; ot < 8; ++ot) acc[mt][ot] = (f32x4){0.f, 0.f, 0.f, 0.f};

  #pragma unroll
  for (int k3 = 0; k3 < 2; ++k3) {
    half8 a[4];
    #pragma unroll
    for (int mt = 0; mt < 4; ++mt)
      a[mt] = *(const half8*)(&aw[(mt*16 + l16)*72 + k3*32 + quad*8]);
    #pragma unroll
    for (int ot = 0; ot < 8; ++ot) {
      half8 b = *(const half8*)(t3Th + (size_t)(n*512 + w*128 + ot*16 + l16)*64 + k3*32 + quad*8);
      #pragma unroll
      for (int mt = 0; mt < 4; ++mt) acc[mt][ot] = mfma16(a[mt], b, acc[mt][ot]);
    }
  }
  #pragma unroll
  for (int k = 0; k < 8; ++k) {
    half8 a[4];
    #pragma unroll
    for (int mt = 0; mt < 4; ++mt)
      a[mt] = *(const half8*)(&xs[(mt*16 + l16)*264 + k*32 + quad*8]);
    #pragma unroll
    for (int ot = 0; ot < 8; ++ot) {
      half8 b = *(const half8*)(Wdh + (size_t)(w*128 + ot*16 + l16)*256 + k*32 + quad*8);
      #pragma unroll
      for (int mt = 0; mt < 4; ++mt) acc[mt][ot] = mfma16(a[mt], b, acc[mt][ot]);
    }
  }

  // ---- epilogue: + bd, store fp32 ----
  #pragma unroll
  for (int ot = 0; ot < 8; ++ot) {
    int o = w*128 + ot*16 + l16;
    float bias = bd[o];
    #pragma unroll
    for (int mt = 0; mt < 4; ++mt)
      #pragma unroll
      for (int r = 0; r < 4; ++r) {
        int m = m0 + mt*16 + quad*4 + r;
        out[(size_t)(n*3136 + m)*512 + o] = acc[mt][ot][r] + bias;
      }
  }
}

// ---------------------------------------------------------------------------
extern "C" void kernel_launch(void* const* d_in, const int* in_sizes, int n_in,
                              void* d_out, int out_size, void* d_ws, size_t ws_size,
                              hipStream_t stream) {
  const float* x  = (const float*)d_in[0];
  const float* t  = (const float*)d_in[1];
  const float* W1 = (const float*)d_in[2];
  const float* W2 = (const float*)d_in[3];
  const float* W3 = (const float*)d_in[4];
  const float* b3 = (const float*)d_in[5];
  const float* Wd = (const float*)d_in[6];
  const float* bd = (const float*)d_in[7];
  float* out = (float*)d_out;

  // workspace layout (bytes), ~2.9 MB total
  char* ws = (char*)d_ws;
  u16* W1h  = (u16*)(ws + 0);        //  256*256*2 = 131072
  u16* W2h  = (u16*)(ws + 131072);   //  131072
  u16* W3h  = (u16*)(ws + 262144);   //  512*256*2 = 262144
  u16* Wdh  = (u16*)(ws + 524288);   //  262144
  u16* th   = (u16*)(ws + 786432);   //  16*64*256*2 = 524288
  u16* tqh  = (u16*)(ws + 1310720);  //  524288
  u16* t3Th = (u16*)(ws + 1835008);  //  16*512*64*2 = 1048576  (end 2883584)

  hipLaunchKernelGGL(cvt_kernel, dim3(1024), dim3(256), 0, stream,
                     W1, W2, W3, Wd, t, W1h, W2h, W3h, Wdh, th);
  hipLaunchKernelGGL(tq_kernel, dim3(16), dim3(256), 0, stream, th, W2h, tqh);
  hipLaunchKernelGGL(t3t_kernel, dim3(128), dim3(256), 0, stream, th, W3h, b3, t3Th);
  hipLaunchKernelGGL(main_kernel, dim3(784), dim3(256), 0, stream,
                     x, W1h, Wdh, tqh, t3Th, bd, out);
}

// Round 2
// 238.564 us; speedup vs baseline: 1.0664x; 1.0664x over previous
//
#include <hip/hip_runtime.h>

// Projector: out[n,p,o] = x@Wd^T + bd + softmax_l((x@W1^T)·(t@W2^T)^T) @ (t@W3^T + b3)
// N=16, HW=3136 (=49*64), L=64, C_IN=256, C_OUT=512, D=256. fp32 in/out.
// All GEMMs via v_mfma_f32_16x16x32_f16 (f16 staging, fp32 accum).
// R2: 512-thread blocks (8 waves), wave owns 64x64 out tile (64 AGPR acc vs
// 128), xq/aw LDS aliased -> 51.2 KB, launch_bounds(512,4) caps regs at 128
// -> target 2 blocks x 8 waves = 16 waves/CU (50%) vs R1's 8 waves (25%).

typedef unsigned short u16;
using half8 = __attribute__((ext_vector_type(8))) _Float16;
using f32x4 = __attribute__((ext_vector_type(4))) float;

__device__ __forceinline__ u16 f2h(float f) {
  _Float16 h = (_Float16)f;            // RNE
  union { _Float16 h; u16 u; } cv; cv.h = h;
  return cv.u;
}

__device__ __forceinline__ f32x4 mfma16(half8 a, half8 b, f32x4 c) {
  return __builtin_amdgcn_mfma_f32_16x16x32_f16(a, b, c, 0, 0, 0);
}

// ---------------------------------------------------------------------------
// K0: fp32 -> f16 conversion of W1, W2, W3, Wd, t
// ---------------------------------------------------------------------------
__global__ __launch_bounds__(256) void cvt_kernel(
    const float* __restrict__ W1, const float* __restrict__ W2,
    const float* __restrict__ W3, const float* __restrict__ Wd,
    const float* __restrict__ t,
    u16* __restrict__ W1h, u16* __restrict__ W2h, u16* __restrict__ W3h,
    u16* __restrict__ Wdh, u16* __restrict__ th) {
  int i = blockIdx.x * 256 + threadIdx.x;   // grid covers 262144
  if (i < 65536)  { W1h[i] = f2h(W1[i]); W2h[i] = f2h(W2[i]); }
  if (i < 131072) { W3h[i] = f2h(W3[i]); Wdh[i] = f2h(Wd[i]); }
  if (i < 262144) { th[i]  = f2h(t[i]); }
}

// ---------------------------------------------------------------------------
// K1: t_q[n,l,e] = sum_d t[n,l,d] * W2[e,d] -> f16 row-major over e
// R2 regrid: 64 blocks (n, e-quarter); wave w owns 16 e-cols.
// ---------------------------------------------------------------------------
__global__ __launch_bounds__(256) void tq_kernel(
    const u16* __restrict__ th, const u16* __restrict__ W2h,
    u16* __restrict__ tqh) {
  const int n = blockIdx.x >> 2, eb = blockIdx.x & 3;
  const int tid = threadIdx.x, w = tid >> 6, lane = tid & 63;
  const int quad = lane >> 4, l16 = lane & 15;
  const int e0 = eb*64 + w*16;

  f32x4 acc[4];
  #pragma unroll
  for (int mt = 0; mt < 4; ++mt) acc[mt] = (f32x4){0.f, 0.f, 0.f, 0.f};

  #pragma unroll
  for (int k = 0; k < 8; ++k) {
    half8 b = *(const half8*)(W2h + (size_t)(e0 + l16)*256 + k*32 + quad*8);
    #pragma unroll
    for (int mt = 0; mt < 4; ++mt) {
      half8 a = *(const half8*)(th + (size_t)(n*64 + mt*16 + l16)*256 + k*32 + quad*8);
      acc[mt] = mfma16(a, b, acc[mt]);
    }
  }
  #pragma unroll
  for (int mt = 0; mt < 4; ++mt)
    #pragma unroll
    for (int r = 0; r < 4; ++r) {
      int l = mt*16 + quad*4 + r;
      tqh[(size_t)(n*64 + l)*256 + e0 + l16] = f2h(acc[mt][r]);
    }
}

// ---------------------------------------------------------------------------
// K2: t3T[n,o,l] = sum_d W3[o,d]*t[n,l,d] + b3[o]  (directly transposed:
// A = W3 rows (m=o), B = t rows (n=l)). grid 16*8.
// ---------------------------------------------------------------------------
__global__ __launch_bounds__(256) void t3t_kernel(
    const u16* __restrict__ th, const u16* __restrict__ W3h,
    const float* __restrict__ b3, u16* __restrict__ t3Th) {
  const int n = blockIdx.x >> 3, ob = blockIdx.x & 7;
  const int tid = threadIdx.x, w = tid >> 6, lane = tid & 63;
  const int quad = lane >> 4, l16 = lane & 15;
  const int o0 = ob*64 + w*16;

  f32x4 acc[4];
  #pragma unroll
  for (int nt = 0; nt < 4; ++nt) acc[nt] = (f32x4){0.f, 0.f, 0.f, 0.f};

  #pragma unroll
  for (int k = 0; k < 8; ++k) {
    half8 a = *(const half8*)(W3h + (size_t)(o0 + l16)*256 + k*32 + quad*8);
    #pragma unroll
    for (int nt = 0; nt < 4; ++nt) {
      half8 b = *(const half8*)(th + (size_t)(n*64 + nt*16 + l16)*256 + k*32 + quad*8);
      acc[nt] = mfma16(a, b, acc[nt]);
    }
  }
  #pragma unroll
  for (int nt = 0; nt < 4; ++nt)
    #pragma unroll
    for (int r = 0; r < 4; ++r) {
      int o = o0 + quad*4 + r;
      int l = nt*16 + l16;
      t3Th[(size_t)(n*512 + o)*64 + l] = f2h(acc[nt][r] + b3[o]);
    }
}

// ---------------------------------------------------------------------------
// K3: main fused kernel. grid 784 = 16 n * 49 row-tiles of 64; 512 threads.
// LDS: xs 64x264 u16 (33,792 B; stride 264 = 4 banks mod 32, 2-way free),
//      xqaw 64x136 u16 (17,408 B) aliased: xq (stride 136) then aw (stride 72).
// Total 51,200 B -> LDS allows 3 blocks/CU; regs cap at 2 blocks (16 waves).
// ---------------------------------------------------------------------------
__global__ __launch_bounds__(512, 4) void main_kernel(
    const float* __restrict__ x, const u16* __restrict__ W1h,
    const u16* __restrict__ Wdh, const u16* __restrict__ tqh,
    const u16* __restrict__ t3Th, const float* __restrict__ bd,
    float* __restrict__ out) {
  __shared__ u16 xs[64*264];
  __shared__ u16 xqaw[64*136];   // aliased: xq(64x136) / aw(64x72)

  const int bid = blockIdx.x;
  const int n = bid / 49;
  const int pt = bid - n*49;
  const int m0 = pt * 64;
  const int tid = threadIdx.x, w = tid >> 6, lane = tid & 63;
  const int quad = lane >> 4, l16 = lane & 15;

  // ---- stage x tile: 64x256 fp32 -> f16 LDS (coalesced float4) ----
  {
    const float4* xg = (const float4*)(x + (size_t)(n*3136 + m0)*256);
    #pragma unroll
    for (int it = 0; it < 8; ++it) {
      int idx = it*512 + tid;
      int r = idx >> 6, c4 = idx & 63;
      float4 v = xg[idx];
      ushort4 u;
      u.x = f2h(v.x); u.y = f2h(v.y); u.z = f2h(v.z); u.w = f2h(v.w);
      *(ushort4*)(&xs[r*264 + c4*4]) = u;
    }
  }
  __syncthreads();

  f32x4 acc2[4];
  #pragma unroll
  for (int lt = 0; lt < 4; ++lt) acc2[lt] = (f32x4){0.f, 0.f, 0.f, 0.f};

  // ---- GEMM1 (x_q = x@W1^T) + GEMM2 (scores = x_q@t_q^T), K-halved ----
  // 8 waves: GEMM1 wave owns 16 e-cols per half; GEMM2 only waves 0-3.
  #pragma unroll
  for (int h = 0; h < 2; ++h) {
    f32x4 acc1[4];
    #pragma unroll
    for (int mt = 0; mt < 4; ++mt) acc1[mt] = (f32x4){0.f, 0.f, 0.f, 0.f};

    #pragma unroll
    for (int k = 0; k < 8; ++k) {
      half8 b = *(const half8*)(W1h + (size_t)(h*128 + w*16 + l16)*256 + k*32 + quad*8);
      #pragma unroll
      for (int mt = 0; mt < 4; ++mt) {
        half8 a = *(const half8*)(&xs[(mt*16 + l16)*264 + k*32 + quad*8]);
        acc1[mt] = mfma16(a, b, acc1[mt]);
      }
    }
    __syncthreads();  // prior iteration's xq fully consumed by all waves
    #pragma unroll
    for (int mt = 0; mt < 4; ++mt)
      #pragma unroll
      for (int r = 0; r < 4; ++r)
        xqaw[(mt*16 + quad*4 + r)*136 + w*16 + l16] = f2h(acc1[mt][r]);
    __syncthreads();

    if (w < 4) {
      #pragma unroll
      for (int k2 = 0; k2 < 4; ++k2) {
        half8 a = *(const half8*)(&xqaw[(w*16 + l16)*136 + k2*32 + quad*8]);
        #pragma unroll
        for (int lt = 0; lt < 4; ++lt) {
          half8 b = *(const half8*)(tqh + (size_t)(n*64 + lt*16 + l16)*256 + h*128 + k2*32 + quad*8);
          acc2[lt] = mfma16(a, b, acc2[lt]);
        }
      }
    }
  }
  __syncthreads();  // all GEMM2 reads of xq done before aw overwrites it

  // ---- softmax over l (waves 0-3; row m = w*16+quad*4+r; shfl_xor 1..8
  //      stay within the 16-lane l16 group) ----
  if (w < 4) {
    #pragma unroll
    for (int r = 0; r < 4; ++r) {
      float s0 = acc2[0][r], s1 = acc2[1][r], s2 = acc2[2][r], s3 = acc2[3][r];
      float mx = fmaxf(fmaxf(s0, s1), fmaxf(s2, s3));
      #pragma unroll
      for (int off = 8; off >= 1; off >>= 1) mx = fmaxf(mx, __shfl_xor(mx, off, 64));
      float e0 = __expf(s0 - mx), e1 = __expf(s1 - mx);
      float e2 = __expf(s2 - mx), e3 = __expf(s3 - mx);
      float s = e0 + e1 + e2 + e3;
      #pragma unroll
      for (int off = 8; off >= 1; off >>= 1) s += __shfl_xor(s, off, 64);
      float inv = 1.0f / s;
      int row = (w*16 + quad*4 + r)*72;
      xqaw[row +  0 + l16] = f2h(e0 * inv);
      xqaw[row + 16 + l16] = f2h(e1 * inv);
      xqaw[row + 32 + l16] = f2h(e2 * inv);
      xqaw[row + 48 + l16] = f2h(e3 * inv);
    }
  }
  __syncthreads();

  // ---- GEMM3 (probs @ t3) + GEMM4 (x @ Wd^T) share one accumulator;
  //      wave w owns output cols [64w, 64w+64) -> acc[4][4] = 64 AGPRs ----
  f32x4 acc[4][4];
  #pragma unroll
  for (int mt = 0; mt < 4; ++mt)
    #pragma unroll
    for (int ot = 0; ot < 4; ++ot) acc[mt][ot] = (f32x4){0.f, 0.f, 0.f, 0.f};

  #pragma unroll
  for (int k3 = 0; k3 < 2; ++k3) {
    half8 a[4];
    #pragma unroll
    for (int mt = 0; mt < 4; ++mt)
      a[mt] = *(const half8*)(&xqaw[(mt*16 + l16)*72 + k3*32 + quad*8]);
    #pragma unroll
    for (int ot = 0; ot < 4; ++ot) {
      half8 b = *(const half8*)(t3Th + (size_t)(n*512 + w*64 + ot*16 + l16)*64 + k3*32 + quad*8);
      #pragma unroll
      for (int mt = 0; mt < 4; ++mt) acc[mt][ot] = mfma16(a[mt], b, acc[mt][ot]);
    }
  }
  #pragma unroll
  for (int k = 0; k < 8; ++k) {
    half8 a[4];
    #pragma unroll
    for (int mt = 0; mt < 4; ++mt)
      a[mt] = *(const half8*)(&xs[(mt*16 + l16)*264 + k*32 + quad*8]);
    #pragma unroll
    for (int ot = 0; ot < 4; ++ot) {
      half8 b = *(const half8*)(Wdh + (size_t)(w*64 + ot*16 + l16)*256 + k*32 + quad*8);
      #pragma unroll
      for (int mt = 0; mt < 4; ++mt) acc[mt][ot] = mfma16(a[mt], b, acc[mt][ot]);
    }
  }

  // ---- epilogue: + bd, store fp32 ----
  #pragma unroll
  for (int ot = 0; ot < 4; ++ot) {
    int o = w*64 + ot*16 + l16;
    float bias = bd[o];
    #pragma unroll
    for (int mt = 0; mt < 4; ++mt)
      #pragma unroll
      for (int r = 0; r < 4; ++r) {
        int m = m0 + mt*16 + quad*4 + r;
        out[(size_t)(n*3136 + m)*512 + o] = acc[mt][ot][r] + bias;
      }
  }
}

// ---------------------------------------------------------------------------
extern "C" void kernel_launch(void* const* d_in, const int* in_sizes, int n_in,
                              void* d_out, int out_size, void* d_ws, size_t ws_size,
                              hipStream_t stream) {
  const float* x  = (const float*)d_in[0];
  const float* t  = (const float*)d_in[1];
  const float* W1 = (const float*)d_in[2];
  const float* W2 = (const float*)d_in[3];
  const float* W3 = (const float*)d_in[4];
  const float* b3 = (const float*)d_in[5];
  const float* Wd = (const float*)d_in[6];
  const float* bd = (const float*)d_in[7];
  float* out = (float*)d_out;

  // workspace layout (bytes), ~2.9 MB total
  char* ws = (char*)d_ws;
  u16* W1h  = (u16*)(ws + 0);        //  256*256*2 = 131072
  u16* W2h  = (u16*)(ws + 131072);   //  131072
  u16* W3h  = (u16*)(ws + 262144);   //  512*256*2 = 262144
  u16* Wdh  = (u16*)(ws + 524288);   //  262144
  u16* th   = (u16*)(ws + 786432);   //  16*64*256*2 = 524288
  u16* tqh  = (u16*)(ws + 1310720);  //  524288
  u16* t3Th = (u16*)(ws + 1835008);  //  16*512*64*2 = 1048576  (end 2883584)

  hipLaunchKernelGGL(cvt_kernel, dim3(1024), dim3(256), 0, stream,
                     W1, W2, W3, Wd, t, W1h, W2h, W3h, Wdh, th);
  hipLaunchKernelGGL(tq_kernel, dim3(64), dim3(256), 0, stream, th, W2h, tqh);
  hipLaunchKernelGGL(t3t_kernel, dim3(128), dim3(256), 0, stream, th, W3h, b3, t3Th);
  hipLaunchKernelGGL(main_kernel, dim3(784), dim3(512), 0, stream,
                     x, W1h, Wdh, tqh, t3Th, bd, out);
}

// Round 3
// 200.398 us; speedup vs baseline: 1.2695x; 1.1904x over previous
//
#include <hip/hip_runtime.h>

// Projector: out[n,p,o] = x@Wd^T + bd + softmax_l((x@W1^T)·(t@W2^T)^T) @ (t@W3^T + b3)
// N=16, HW=3136 (=49*64), L=64, C_IN=256, C_OUT=512, D=256. fp32 in/out.
// All GEMMs via v_mfma_f32_16x16x32_f16 (f16 staging, fp32 accum).
// R3: every global access lane-contiguous. All B operands pre-blocked into
// "fragment-linear" (FL) layout: flat = ((row/16)*KC + k/32)*512 + quad*128 +
// (row%16)*8 + k%8  (quad=(k%32)/8), so each wave's MFMA B-fragment load is
// one contiguous 1 KB global read. Epilogue stores coalesced via LDS transpose.
// Theory: R1/R2's ~1000 scattered (16-segment) VMEM instrs/block were the
// bottleneck (occupancy 2x in R2 changed nothing; all pipes <20% busy).

typedef unsigned short u16;
using half8 = __attribute__((ext_vector_type(8))) _Float16;
using f32x4 = __attribute__((ext_vector_type(4))) float;

__device__ __forceinline__ u16 f2h(float f) {
  _Float16 h = (_Float16)f;            // RNE
  union { _Float16 h; u16 u; } cv; cv.h = h;
  return cv.u;
}

__device__ __forceinline__ f32x4 mfma16(half8 a, half8 b, f32x4 c) {
  return __builtin_amdgcn_mfma_f32_16x16x32_f16(a, b, c, 0, 0, 0);
}

// ---------------------------------------------------------------------------
// K0: fp32 -> f16 + reblock into fragment-linear layout (K=256, KC=8).
// One block per source row (coalesced 1 KB row read; small scattered u16
// writes are fine at this scale). Rows: W1 256 | W2 256 | W3 512 | Wd 512 |
// t 1024  => 2560 blocks.
// ---------------------------------------------------------------------------
__global__ __launch_bounds__(256) void reblock_kernel(
    const float* __restrict__ W1, const float* __restrict__ W2,
    const float* __restrict__ W3, const float* __restrict__ Wd,
    const float* __restrict__ t,
    u16* __restrict__ W1f, u16* __restrict__ W2f, u16* __restrict__ W3f,
    u16* __restrict__ Wdf, u16* __restrict__ tf) {
  int b = blockIdx.x, k = threadIdx.x;
  const float* src; u16* dst; int row;
  if (b < 256)       { src = W1; dst = W1f; row = b; }
  else if (b < 512)  { src = W2; dst = W2f; row = b - 256; }
  else if (b < 1024) { src = W3; dst = W3f; row = b - 512; }
  else if (b < 1536) { src = Wd; dst = Wdf; row = b - 1024; }
  else               { src = t;  dst = tf;  row = b - 1536; }
  float v = src[(size_t)row*256 + k];
  int flat = ((row >> 4)*8 + (k >> 5))*512 + ((k >> 3) & 3)*128 + (row & 15)*8 + (k & 7);
  dst[flat] = f2h(v);
}

// ---------------------------------------------------------------------------
// K1: merged t_q and t3 kernels, all operands FL, outputs written FL.
// blocks 0..63:   tq[n,l,e] = t@W2^T        -> tqf (rows=l per n, K=e=256)
// blocks 64..191: t3[n,o,l] = t@W3^T + b3   -> t3f (rows=o per n, K=l=64)
// ---------------------------------------------------------------------------
__global__ __launch_bounds__(256) void tq_t3t_kernel(
    const u16* __restrict__ tf, const u16* __restrict__ W2f,
    const u16* __restrict__ W3f, const float* __restrict__ b3,
    u16* __restrict__ tqf, u16* __restrict__ t3f) {
  const int tid = threadIdx.x, w = tid >> 6, lane = tid & 63;
  const int quad = lane >> 4, l16 = lane & 15;
  const int b = blockIdx.x;

  if (b < 64) {
    const int n = b >> 2, eb = b & 3;
    const int gW2 = eb*4 + w;          // e-row group (e0 = eb*64 + w*16)
    f32x4 acc[4];
    #pragma unroll
    for (int mt = 0; mt < 4; ++mt) acc[mt] = (f32x4){0.f, 0.f, 0.f, 0.f};
    #pragma unroll
    for (int kc = 0; kc < 8; ++kc) {
      half8 bf = *(const half8*)(W2f + (gW2*8 + kc)*512 + lane*8);
      #pragma unroll
      for (int mt = 0; mt < 4; ++mt) {
        half8 a = *(const half8*)(tf + ((n*4 + mt)*8 + kc)*512 + lane*8);
        acc[mt] = mfma16(a, bf, acc[mt]);
      }
    }
    // value at (l = mt*16+quad*4+r, e = eb*64+w*16+l16); write FL for GEMM2
    #pragma unroll
    for (int mt = 0; mt < 4; ++mt)
      #pragma unroll
      for (int r = 0; r < 4; ++r) {
        int flat = ((n*4 + mt)*8 + eb*2 + (w >> 1))*512
                 + ((w & 1)*2 + (l16 >> 3))*128 + (quad*4 + r)*8 + (l16 & 7);
        tqf[flat] = f2h(acc[mt][r]);
      }
  } else {
    const int b2 = b - 64;
    const int n = b2 >> 3, ob = b2 & 7;
    const int gW3 = ob*4 + w;          // o-row group (o0 = ob*64 + w*16)
    f32x4 acc[4];
    #pragma unroll
    for (int nt = 0; nt < 4; ++nt) acc[nt] = (f32x4){0.f, 0.f, 0.f, 0.f};
    #pragma unroll
    for (int kc = 0; kc < 8; ++kc) {
      half8 a = *(const half8*)(W3f + (gW3*8 + kc)*512 + lane*8);
      #pragma unroll
      for (int nt = 0; nt < 4; ++nt) {
        half8 bf = *(const half8*)(tf + ((n*4 + nt)*8 + kc)*512 + lane*8);
        acc[nt] = mfma16(a, bf, acc[nt]);
      }
    }
    // value at (o = ob*64+w*16+quad*4+r, l = nt*16+l16); write FL for GEMM3
    #pragma unroll
    for (int nt = 0; nt < 4; ++nt)
      #pragma unroll
      for (int r = 0; r < 4; ++r) {
        int o = ob*64 + w*16 + quad*4 + r;
        int flat = ((n*32 + ob*4 + w)*2 + (nt >> 1))*512
                 + ((nt & 1)*2 + (l16 >> 3))*128 + (quad*4 + r)*8 + (l16 & 7);
        t3f[flat] = f2h(acc[nt][r] + b3[o]);
      }
  }
}

// ---------------------------------------------------------------------------
// K2: main fused kernel. grid 784 = 16 n * 49 row-tiles of 64; 512 threads.
// LDS: xs 64x264 u16 (33,792 B; row stride = 4 banks mod 32 -> 2-way free),
//      pool 17,408 B reused as xq(64x136 u16) -> aw(64x72 u16) -> epi(8x520 f32).
// Total 51,200 B. All global loads/stores lane-contiguous.
// ---------------------------------------------------------------------------
__global__ __launch_bounds__(512, 4) void main_kernel(
    const float* __restrict__ x, const u16* __restrict__ W1f,
    const u16* __restrict__ Wdf, const u16* __restrict__ tqf,
    const u16* __restrict__ t3f, const float* __restrict__ bd,
    float* __restrict__ out) {
  __shared__ u16 xs[64*264];
  __shared__ __align__(16) u16 pool[64*136];

  const int bid = blockIdx.x;
  const int n = bid / 49;
  const int pt = bid - n*49;
  const int m0 = pt * 64;
  const int tid = threadIdx.x, w = tid >> 6, lane = tid & 63;
  const int quad = lane >> 4, l16 = lane & 15;

  float bias[4];
  #pragma unroll
  for (int ot = 0; ot < 4; ++ot) bias[ot] = bd[w*64 + ot*16 + l16];

  // ---- stage x tile: 64x256 fp32 -> f16 LDS (coalesced float4) ----
  {
    const float4* xg = (const float4*)(x + (size_t)(n*3136 + m0)*256);
    #pragma unroll
    for (int it = 0; it < 8; ++it) {
      int idx = it*512 + tid;
      int r = idx >> 6, c4 = idx & 63;
      float4 v = xg[idx];
      ushort4 u;
      u.x = f2h(v.x); u.y = f2h(v.y); u.z = f2h(v.z); u.w = f2h(v.w);
      *(ushort4*)(&xs[r*264 + c4*4]) = u;
    }
  }
  __syncthreads();

  f32x4 acc2[4];
  #pragma unroll
  for (int lt = 0; lt < 4; ++lt) acc2[lt] = (f32x4){0.f, 0.f, 0.f, 0.f};

  // ---- GEMM1 (x_q = x@W1^T, B from FL) + GEMM2 (scores, B from FL) ----
  #pragma unroll
  for (int h = 0; h < 2; ++h) {
    f32x4 acc1[4];
    #pragma unroll
    for (int mt = 0; mt < 4; ++mt) acc1[mt] = (f32x4){0.f, 0.f, 0.f, 0.f};

    const u16* w1p = W1f + (h*8 + w)*8*512;   // e-row group h*8+w
    #pragma unroll
    for (int kc = 0; kc < 8; ++kc) {
      half8 bf = *(const half8*)(w1p + kc*512 + lane*8);   // contiguous 1 KB
      #pragma unroll
      for (int mt = 0; mt < 4; ++mt) {
        half8 a = *(const half8*)(&xs[(mt*16 + l16)*264 + kc*32 + quad*8]);
        acc1[mt] = mfma16(a, bf, acc1[mt]);
      }
    }
    __syncthreads();  // prior GEMM2 reads of xq done
    #pragma unroll
    for (int mt = 0; mt < 4; ++mt)
      #pragma unroll
      for (int r = 0; r < 4; ++r)
        pool[(mt*16 + quad*4 + r)*136 + w*16 + l16] = f2h(acc1[mt][r]);
    __syncthreads();

    if (w < 4) {
      #pragma unroll
      for (int k2 = 0; k2 < 4; ++k2) {
        half8 a = *(const half8*)(&pool[(w*16 + l16)*136 + k2*32 + quad*8]);
        #pragma unroll
        for (int lt = 0; lt < 4; ++lt) {
          half8 bf = *(const half8*)(tqf + ((n*4 + lt)*8 + h*4 + k2)*512 + lane*8);
          acc2[lt] = mfma16(a, bf, acc2[lt]);
        }
      }
    }
  }
  __syncthreads();   // GEMM2 done before aw overwrites xq region

  // ---- softmax over l (waves 0-3) -> aw in pool (stride 72) ----
  if (w < 4) {
    #pragma unroll
    for (int r = 0; r < 4; ++r) {
      float s0 = acc2[0][r], s1 = acc2[1][r], s2 = acc2[2][r], s3 = acc2[3][r];
      float mx = fmaxf(fmaxf(s0, s1), fmaxf(s2, s3));
      #pragma unroll
      for (int off = 8; off >= 1; off >>= 1) mx = fmaxf(mx, __shfl_xor(mx, off, 64));
      float e0 = __expf(s0 - mx), e1 = __expf(s1 - mx);
      float e2 = __expf(s2 - mx), e3 = __expf(s3 - mx);
      float s = e0 + e1 + e2 + e3;
      #pragma unroll
      for (int off = 8; off >= 1; off >>= 1) s += __shfl_xor(s, off, 64);
      float inv = 1.0f / s;
      int row = (w*16 + quad*4 + r)*72;
      pool[row +  0 + l16] = f2h(e0 * inv);
      pool[row + 16 + l16] = f2h(e1 * inv);
      pool[row + 32 + l16] = f2h(e2 * inv);
      pool[row + 48 + l16] = f2h(e3 * inv);
    }
  }
  __syncthreads();

  // ---- GEMM3 (probs@t3, B from FL) + GEMM4 (x@Wd^T, B from FL) ----
  f32x4 acc[4][4];
  #pragma unroll
  for (int mt = 0; mt < 4; ++mt)
    #pragma unroll
    for (int ot = 0; ot < 4; ++ot) acc[mt][ot] = (f32x4){0.f, 0.f, 0.f, 0.f};

  #pragma unroll
  for (int kc3 = 0; kc3 < 2; ++kc3) {
    half8 a[4];
    #pragma unroll
    for (int mt = 0; mt < 4; ++mt)
      a[mt] = *(const half8*)(&pool[(mt*16 + l16)*72 + kc3*32 + quad*8]);
    #pragma unroll
    for (int ot = 0; ot < 4; ++ot) {
      half8 bf = *(const half8*)(t3f + ((n*32 + w*4 + ot)*2 + kc3)*512 + lane*8);
      #pragma unroll
      for (int mt = 0; mt < 4; ++mt) acc[mt][ot] = mfma16(a[mt], bf, acc[mt][ot]);
    }
  }
  #pragma unroll
  for (int kc = 0; kc < 8; ++kc) {
    half8 a[4];
    #pragma unroll
    for (int mt = 0; mt < 4; ++mt)
      a[mt] = *(const half8*)(&xs[(mt*16 + l16)*264 + kc*32 + quad*8]);
    #pragma unroll
    for (int ot = 0; ot < 4; ++ot) {
      half8 bf = *(const half8*)(Wdf + ((w*4 + ot)*8 + kc)*512 + lane*8);
      #pragma unroll
      for (int mt = 0; mt < 4; ++mt) acc[mt][ot] = mfma16(a[mt], bf, acc[mt][ot]);
    }
  }
  __syncthreads();   // all aw reads done before pool reuse as epi buffer

  // ---- epilogue: LDS transpose in 8-row chunks, coalesced float4 stores ----
  float* pf = (float*)pool;              // 8 rows x 520 f32 = 16,640 B
  #pragma unroll
  for (int c = 0; c < 8; ++c) {
    int mt = c >> 1;
    if ((quad >> 1) == (c & 1)) {        // quads holding rows [c*8, c*8+8)
      int rl = (quad & 1)*4;
      #pragma unroll
      for (int ot = 0; ot < 4; ++ot)
        #pragma unroll
        for (int r = 0; r < 4; ++r)
          pf[(rl + r)*520 + w*64 + ot*16 + l16] = acc[mt][ot][r] + bias[ot];
    }
    __syncthreads();
    #pragma unroll
    for (int j = 0; j < 2; ++j) {
      int flat = j*512 + tid;            // 1024 float4 = 8 rows x 128
      int rl = flat >> 7, c4 = (flat & 127)*4;
      float4 v = *(float4*)&pf[rl*520 + c4];
      *(float4*)&out[(size_t)(n*3136 + m0 + c*8 + rl)*512 + c4] = v;
    }
    __syncthreads();
  }
}

// ---------------------------------------------------------------------------
extern "C" void kernel_launch(void* const* d_in, const int* in_sizes, int n_in,
                              void* d_out, int out_size, void* d_ws, size_t ws_size,
                              hipStream_t stream) {
  const float* x  = (const float*)d_in[0];
  const float* t  = (const float*)d_in[1];
  const float* W1 = (const float*)d_in[2];
  const float* W2 = (const float*)d_in[3];
  const float* W3 = (const float*)d_in[4];
  const float* b3 = (const float*)d_in[5];
  const float* Wd = (const float*)d_in[6];
  const float* bd = (const float*)d_in[7];
  float* out = (float*)d_out;

  // workspace layout (bytes), ~2.9 MB total — all fragment-linear f16
  char* ws = (char*)d_ws;
  u16* W1f = (u16*)(ws + 0);        //  131072
  u16* W2f = (u16*)(ws + 131072);   //  131072
  u16* W3f = (u16*)(ws + 262144);   //  262144
  u16* Wdf = (u16*)(ws + 524288);   //  262144
  u16* tf  = (u16*)(ws + 786432);   //  524288
  u16* tqf = (u16*)(ws + 1310720);  //  524288
  u16* t3f = (u16*)(ws + 1835008);  //  1048576  (end 2883584)

  hipLaunchKernelGGL(reblock_kernel, dim3(2560), dim3(256), 0, stream,
                     W1, W2, W3, Wd, t, W1f, W2f, W3f, Wdf, tf);
  hipLaunchKernelGGL(tq_t3t_kernel, dim3(192), dim3(256), 0, stream,
                     tf, W2f, W3f, b3, tqf, t3f);
  hipLaunchKernelGGL(main_kernel, dim3(784), dim3(512), 0, stream,
                     x, W1f, Wdf, tqf, t3f, bd, out);
}

// Round 4
// 196.780 us; speedup vs baseline: 1.2929x; 1.0184x over previous
//
#include <hip/hip_runtime.h>

// Projector: out[n,p,o] = x@Wd^T + bd + softmax_l((x@W1^T)·(t@W2^T)^T) @ (t@W3^T + b3)
// N=16, HW=3136 (=49*64), L=64, C_IN=256, C_OUT=512, D=256. fp32 in/out.
// All GEMMs via v_mfma_f32_16x16x32_f16 (f16 staging, fp32 accum), B operands
// pre-blocked fragment-linear (FL): each wave's B-frag load = contiguous 1 KB.
// R4: barrier-phase reduction 24 -> 6 per block.
//  - epilogue: per-wave LDS transpose (wave-private scratch aliased over dead
//    xs; only lgkmcnt ordering, no s_barrier), 256B-segment float4 stores.
//  - phase merge: GEMM1-h1 || GEMM2-h0; GEMM4 || GEMM2-h1 (fills waves 4-7).
//  - W1f-h0 fragments register-prefetched before the stage barrier.

typedef unsigned short u16;
using half8 = __attribute__((ext_vector_type(8))) _Float16;
using f32x4 = __attribute__((ext_vector_type(4))) float;

__device__ __forceinline__ u16 f2h(float f) {
  _Float16 h = (_Float16)f;            // RNE
  union { _Float16 h; u16 u; } cv; cv.h = h;
  return cv.u;
}

__device__ __forceinline__ f32x4 mfma16(half8 a, half8 b, f32x4 c) {
  return __builtin_amdgcn_mfma_f32_16x16x32_f16(a, b, c, 0, 0, 0);
}

// ---------------------------------------------------------------------------
// K0: fp32 -> f16 + reblock into fragment-linear layout (KC=8 k-chunks).
// flat = ((row/16)*8 + k/32)*512 + ((k/8)%4)*128 + (row%16)*8 + (k%8)
// ---------------------------------------------------------------------------
__global__ __launch_bounds__(256) void reblock_kernel(
    const float* __restrict__ W1, const float* __restrict__ W2,
    const float* __restrict__ W3, const float* __restrict__ Wd,
    const float* __restrict__ t,
    u16* __restrict__ W1f, u16* __restrict__ W2f, u16* __restrict__ W3f,
    u16* __restrict__ Wdf, u16* __restrict__ tf) {
  int b = blockIdx.x, k = threadIdx.x;
  const float* src; u16* dst; int row;
  if (b < 256)       { src = W1; dst = W1f; row = b; }
  else if (b < 512)  { src = W2; dst = W2f; row = b - 256; }
  else if (b < 1024) { src = W3; dst = W3f; row = b - 512; }
  else if (b < 1536) { src = Wd; dst = Wdf; row = b - 1024; }
  else               { src = t;  dst = tf;  row = b - 1536; }
  float v = src[(size_t)row*256 + k];
  int flat = ((row >> 4)*8 + (k >> 5))*512 + ((k >> 3) & 3)*128 + (row & 15)*8 + (k & 7);
  dst[flat] = f2h(v);
}

// ---------------------------------------------------------------------------
// K1: merged t_q and t3 kernels, all operands FL, outputs written FL.
// blocks 0..63:   tq[n,l,e] = t@W2^T        -> tqf (rows=l per n, K=e=256)
// blocks 64..191: t3[n,o,l] = t@W3^T + b3   -> t3f (rows=o per n, K=l=64)
// ---------------------------------------------------------------------------
__global__ __launch_bounds__(256) void tq_t3t_kernel(
    const u16* __restrict__ tf, const u16* __restrict__ W2f,
    const u16* __restrict__ W3f, const float* __restrict__ b3,
    u16* __restrict__ tqf, u16* __restrict__ t3f) {
  const int tid = threadIdx.x, w = tid >> 6, lane = tid & 63;
  const int quad = lane >> 4, l16 = lane & 15;
  const int b = blockIdx.x;

  if (b < 64) {
    const int n = b >> 2, eb = b & 3;
    const int gW2 = eb*4 + w;          // e-row group (e0 = eb*64 + w*16)
    f32x4 acc[4];
    #pragma unroll
    for (int mt = 0; mt < 4; ++mt) acc[mt] = (f32x4){0.f, 0.f, 0.f, 0.f};
    #pragma unroll
    for (int kc = 0; kc < 8; ++kc) {
      half8 bf = *(const half8*)(W2f + (gW2*8 + kc)*512 + lane*8);
      #pragma unroll
      for (int mt = 0; mt < 4; ++mt) {
        half8 a = *(const half8*)(tf + ((n*4 + mt)*8 + kc)*512 + lane*8);
        acc[mt] = mfma16(a, bf, acc[mt]);
      }
    }
    // value at (l = mt*16+quad*4+r, e = eb*64+w*16+l16); write FL for GEMM2
    #pragma unroll
    for (int mt = 0; mt < 4; ++mt)
      #pragma unroll
      for (int r = 0; r < 4; ++r) {
        int flat = ((n*4 + mt)*8 + eb*2 + (w >> 1))*512
                 + ((w & 1)*2 + (l16 >> 3))*128 + (quad*4 + r)*8 + (l16 & 7);
        tqf[flat] = f2h(acc[mt][r]);
      }
  } else {
    const int b2 = b - 64;
    const int n = b2 >> 3, ob = b2 & 7;
    const int gW3 = ob*4 + w;          // o-row group (o0 = ob*64 + w*16)
    f32x4 acc[4];
    #pragma unroll
    for (int nt = 0; nt < 4; ++nt) acc[nt] = (f32x4){0.f, 0.f, 0.f, 0.f};
    #pragma unroll
    for (int kc = 0; kc < 8; ++kc) {
      half8 a = *(const half8*)(W3f + (gW3*8 + kc)*512 + lane*8);
      #pragma unroll
      for (int nt = 0; nt < 4; ++nt) {
        half8 bf = *(const half8*)(tf + ((n*4 + nt)*8 + kc)*512 + lane*8);
        acc[nt] = mfma16(a, bf, acc[nt]);
      }
    }
    // value at (o = ob*64+w*16+quad*4+r, l = nt*16+l16); write FL for GEMM3
    #pragma unroll
    for (int nt = 0; nt < 4; ++nt)
      #pragma unroll
      for (int r = 0; r < 4; ++r) {
        int o = ob*64 + w*16 + quad*4 + r;
        int flat = ((n*32 + ob*4 + w)*2 + (nt >> 1))*512
                 + ((nt & 1)*2 + (l16 >> 3))*128 + (quad*4 + r)*8 + (l16 & 7);
        t3f[flat] = f2h(acc[nt][r] + b3[o]);
      }
  }
}

// ---------------------------------------------------------------------------
// K2: main fused kernel. grid 784 = 16 n * 49 row-tiles of 64; 512 threads.
// smem carve (52,224 B total):
//   [0, 34816): xs 64x264 u16 (33,792 B; stride = 4 banks mod 32, 2-way free)
//               later aliased as per-wave epi scratch f32 16x68 (4352 B/wave)
//   [34816, +17408): pool = xq(64x136 u16) then aw(64x72 u16)
// 6 barriers per block (was 24).
// ---------------------------------------------------------------------------
__global__ __launch_bounds__(512, 4) void main_kernel(
    const float* __restrict__ x, const u16* __restrict__ W1f,
    const u16* __restrict__ Wdf, const u16* __restrict__ tqf,
    const u16* __restrict__ t3f, const float* __restrict__ bd,
    float* __restrict__ out) {
  __shared__ __attribute__((aligned(16))) char smem[34816 + 17408];
  u16* xs   = (u16*)smem;              // 64 x 264
  u16* pool = (u16*)(smem + 34816);    // 64 x 136 / 64 x 72

  const int bid = blockIdx.x;
  const int n = bid / 49;
  const int pt = bid - n*49;
  const int m0 = pt * 64;
  const int tid = threadIdx.x, w = tid >> 6, lane = tid & 63;
  const int quad = lane >> 4, l16 = lane & 15;

  // ---- prefetch W1f h0 fragments (latency overlapped with x staging) ----
  half8 w1a[8];
  {
    const u16* p = W1f + (size_t)w*8*512;      // e-row group w (h=0)
    #pragma unroll
    for (int kc = 0; kc < 8; ++kc) w1a[kc] = *(const half8*)(p + kc*512 + lane*8);
  }
  float bias[4];
  #pragma unroll
  for (int ot = 0; ot < 4; ++ot) bias[ot] = bd[w*64 + ot*16 + l16];

  // ---- stage x tile: 64x256 fp32 -> f16 LDS (coalesced float4) ----
  {
    const float4* xg = (const float4*)(x + (size_t)(n*3136 + m0)*256);
    #pragma unroll
    for (int it = 0; it < 8; ++it) {
      int idx = it*512 + tid;
      int r = idx >> 6, c4 = idx & 63;
      float4 v = xg[idx];
      ushort4 u;
      u.x = f2h(v.x); u.y = f2h(v.y); u.z = f2h(v.z); u.w = f2h(v.w);
      *(ushort4*)(&xs[r*264 + c4*4]) = u;
    }
  }
  __syncthreads();                                             // B1

  // ---- GEMM1 h0 (x_q cols w*16..w*16+15) from prefetched regs ----
  f32x4 acc1[4];
  #pragma unroll
  for (int mt = 0; mt < 4; ++mt) acc1[mt] = (f32x4){0.f, 0.f, 0.f, 0.f};
  #pragma unroll
  for (int kc = 0; kc < 8; ++kc)
    #pragma unroll
    for (int mt = 0; mt < 4; ++mt) {
      half8 a = *(const half8*)(&xs[(mt*16 + l16)*264 + kc*32 + quad*8]);
      acc1[mt] = mfma16(a, w1a[kc], acc1[mt]);
    }
  // write xq h0 (pool first use this block -> no pre-barrier)
  #pragma unroll
  for (int mt = 0; mt < 4; ++mt)
    #pragma unroll
    for (int r = 0; r < 4; ++r)
      pool[(mt*16 + quad*4 + r)*136 + w*16 + l16] = f2h(acc1[mt][r]);
  __syncthreads();                                             // B2

  f32x4 acc2[4];
  #pragma unroll
  for (int lt = 0; lt < 4; ++lt) acc2[lt] = (f32x4){0.f, 0.f, 0.f, 0.f};
  f32x4 acc[4][4];
  #pragma unroll
  for (int mt = 0; mt < 4; ++mt)
    #pragma unroll
    for (int ot = 0; ot < 4; ++ot) acc[mt][ot] = (f32x4){0.f, 0.f, 0.f, 0.f};

  // ---- phase: GEMM1 h1 (all waves) || GEMM2 h0 (waves 0-3) ----
  f32x4 acc1b[4];
  #pragma unroll
  for (int mt = 0; mt < 4; ++mt) acc1b[mt] = (f32x4){0.f, 0.f, 0.f, 0.f};
  {
    const u16* p = W1f + (size_t)(8 + w)*8*512;  // e-row group 8+w (h=1)
    #pragma unroll
    for (int kc = 0; kc < 8; ++kc) {
      half8 bf = *(const half8*)(p + kc*512 + lane*8);
      #pragma unroll
      for (int mt = 0; mt < 4; ++mt) {
        half8 a = *(const half8*)(&xs[(mt*16 + l16)*264 + kc*32 + quad*8]);
        acc1b[mt] = mfma16(a, bf, acc1b[mt]);
      }
    }
  }
  if (w < 4) {
    #pragma unroll
    for (int k2 = 0; k2 < 4; ++k2) {
      half8 a = *(const half8*)(&pool[(w*16 + l16)*136 + k2*32 + quad*8]);
      #pragma unroll
      for (int lt = 0; lt < 4; ++lt) {
        half8 bf = *(const half8*)(tqf + ((n*4 + lt)*8 + 0*4 + k2)*512 + lane*8);
        acc2[lt] = mfma16(a, bf, acc2[lt]);
      }
    }
  }
  __syncthreads();                                             // B3
  // write xq h1
  #pragma unroll
  for (int mt = 0; mt < 4; ++mt)
    #pragma unroll
    for (int r = 0; r < 4; ++r)
      pool[(mt*16 + quad*4 + r)*136 + w*16 + l16] = f2h(acc1b[mt][r]);
  __syncthreads();                                             // B4

  // ---- phase: GEMM2 h1 (waves 0-3) || GEMM4 x@Wd^T (all waves) ----
  if (w < 4) {
    #pragma unroll
    for (int k2 = 0; k2 < 4; ++k2) {
      half8 a = *(const half8*)(&pool[(w*16 + l16)*136 + k2*32 + quad*8]);
      #pragma unroll
      for (int lt = 0; lt < 4; ++lt) {
        half8 bf = *(const half8*)(tqf + ((n*4 + lt)*8 + 1*4 + k2)*512 + lane*8);
        acc2[lt] = mfma16(a, bf, acc2[lt]);
      }
    }
  }
  #pragma unroll
  for (int kc = 0; kc < 8; ++kc) {
    half8 a[4];
    #pragma unroll
    for (int mt = 0; mt < 4; ++mt)
      a[mt] = *(const half8*)(&xs[(mt*16 + l16)*264 + kc*32 + quad*8]);
    #pragma unroll
    for (int ot = 0; ot < 4; ++ot) {
      half8 bf = *(const half8*)(Wdf + ((w*4 + ot)*8 + kc)*512 + lane*8);
      #pragma unroll
      for (int mt = 0; mt < 4; ++mt) acc[mt][ot] = mfma16(a[mt], bf, acc[mt][ot]);
    }
  }
  __syncthreads();   // B5: all pool reads (GEMM2) + xs reads (GEMM4) done

  // ---- softmax over l (waves 0-3) -> aw in pool (stride 72) ----
  if (w < 4) {
    #pragma unroll
    for (int r = 0; r < 4; ++r) {
      float s0 = acc2[0][r], s1 = acc2[1][r], s2 = acc2[2][r], s3 = acc2[3][r];
      float mx = fmaxf(fmaxf(s0, s1), fmaxf(s2, s3));
      #pragma unroll
      for (int off = 8; off >= 1; off >>= 1) mx = fmaxf(mx, __shfl_xor(mx, off, 64));
      float e0 = __expf(s0 - mx), e1 = __expf(s1 - mx);
      float e2 = __expf(s2 - mx), e3 = __expf(s3 - mx);
      float s = e0 + e1 + e2 + e3;
      #pragma unroll
      for (int off = 8; off >= 1; off >>= 1) s += __shfl_xor(s, off, 64);
      float inv = 1.0f / s;
      int row = (w*16 + quad*4 + r)*72;
      pool[row +  0 + l16] = f2h(e0 * inv);
      pool[row + 16 + l16] = f2h(e1 * inv);
      pool[row + 32 + l16] = f2h(e2 * inv);
      pool[row + 48 + l16] = f2h(e3 * inv);
    }
  }
  __syncthreads();                                             // B6

  // ---- GEMM3 (probs @ t3) into shared accumulator ----
  #pragma unroll
  for (int kc3 = 0; kc3 < 2; ++kc3) {
    half8 a[4];
    #pragma unroll
    for (int mt = 0; mt < 4; ++mt)
      a[mt] = *(const half8*)(&pool[(mt*16 + l16)*72 + kc3*32 + quad*8]);
    #pragma unroll
    for (int ot = 0; ot < 4; ++ot) {
      half8 bf = *(const half8*)(t3f + ((n*32 + w*4 + ot)*2 + kc3)*512 + lane*8);
      #pragma unroll
      for (int mt = 0; mt < 4; ++mt) acc[mt][ot] = mfma16(a[mt], bf, acc[mt][ot]);
    }
  }

  // ---- epilogue: per-wave transpose in wave-private scratch (over dead xs;
  //      xs reads all completed at B5; pool untouched). NO block barriers. ----
  float* sc = (float*)smem + w*1088;   // 16 x 68 f32 = 4352 B per wave
  #pragma unroll
  for (int mt = 0; mt < 4; ++mt) {
    #pragma unroll
    for (int ot = 0; ot < 4; ++ot)
      #pragma unroll
      for (int r = 0; r < 4; ++r)
        sc[(quad*4 + r)*68 + ot*16 + l16] = acc[mt][ot][r] + bias[ot];
    // compiler inserts lgkmcnt for the WAR/RAW hazards below (wave-local)
    #pragma unroll
    for (int i = 0; i < 4; ++i) {
      float4 v = *(float4*)&sc[(i*4 + quad)*68 + l16*4];
      *(float4*)&out[(size_t)(n*3136 + m0 + mt*16 + i*4 + quad)*512 + w*64 + l16*4] = v;
    }
  }
}

// ---------------------------------------------------------------------------
extern "C" void kernel_launch(void* const* d_in, const int* in_sizes, int n_in,
                              void* d_out, int out_size, void* d_ws, size_t ws_size,
                              hipStream_t stream) {
  const float* x  = (const float*)d_in[0];
  const float* t  = (const float*)d_in[1];
  const float* W1 = (const float*)d_in[2];
  const float* W2 = (const float*)d_in[3];
  const float* W3 = (const float*)d_in[4];
  const float* b3 = (const float*)d_in[5];
  const float* Wd = (const float*)d_in[6];
  const float* bd = (const float*)d_in[7];
  float* out = (float*)d_out;

  // workspace layout (bytes), ~2.9 MB total — all fragment-linear f16
  char* ws = (char*)d_ws;
  u16* W1f = (u16*)(ws + 0);        //  131072
  u16* W2f = (u16*)(ws + 131072);   //  131072
  u16* W3f = (u16*)(ws + 262144);   //  262144
  u16* Wdf = (u16*)(ws + 524288);   //  262144
  u16* tf  = (u16*)(ws + 786432);   //  524288
  u16* tqf = (u16*)(ws + 1310720);  //  524288
  u16* t3f = (u16*)(ws + 1835008);  //  1048576  (end 2883584)

  hipLaunchKernelGGL(reblock_kernel, dim3(2560), dim3(256), 0, stream,
                     W1, W2, W3, Wd, t, W1f, W2f, W3f, Wdf, tf);
  hipLaunchKernelGGL(tq_t3t_kernel, dim3(192), dim3(256), 0, stream,
                     tf, W2f, W3f, b3, tqf, t3f);
  hipLaunchKernelGGL(main_kernel, dim3(784), dim3(512), 0, stream,
                     x, W1f, Wdf, tqf, t3f, bd, out);
}